// Round 7
// baseline (350.309 us; speedup 1.0000x reference)
//
#include <hip/hip_runtime.h>
#include <cstddef>
#include <cstdint>

#define EPSBN 1e-5f
#define LOG2E 1.4426950408889634f

typedef __attribute__((ext_vector_type(8))) __bf16 bf16x8;
typedef __attribute__((ext_vector_type(8))) short short8v;
typedef __attribute__((ext_vector_type(4))) float f32x4;

// ---------------- workspace layout (in floats) ----------------
static constexpr size_t SZ_WB2 = 294912;     // conv1 wb: 4608*128 ushorts / 2
static constexpr size_t SZ_WT2 = 36864;      // conv2 wb
static constexpr size_t SZ_Y   = 2097152;    // 4*128*4096 fp32
static constexpr size_t SZ_QK  = 262144;     // 4*4096*32 ushorts / 2

static constexpr size_t OFF_WB2P = 0;
static constexpr size_t OFF_B1P  = OFF_WB2P + SZ_WB2;
static constexpr size_t OFF_WB2C = OFF_B1P + 128;
static constexpr size_t OFF_B1C  = OFF_WB2C + SZ_WB2;
static constexpr size_t OFF_WT2P = OFF_B1C + 128;
static constexpr size_t OFF_B2P  = OFF_WT2P + SZ_WT2;
static constexpr size_t OFF_WT2C = OFF_B2P + 32;
static constexpr size_t OFF_B2C  = OFF_WT2C + SZ_WT2;
static constexpr size_t OFF_YP   = OFF_B2C + 32;
static constexpr size_t OFF_YC   = OFF_YP + SZ_Y;
static constexpr size_t OFF_Q    = OFF_YC + SZ_Y;      // Qb bf16 [4][4096][32] (pre-scaled by log2e)
static constexpr size_t OFF_K    = OFF_Q + SZ_QK;      // Kb bf16 [4][4096][32]
static constexpr size_t OFF_V    = OFF_K + SZ_QK;      // VF bf16 frag stream, 4MB
static constexpr size_t OFF_PB   = OFF_V + SZ_Y;       // Pb bf16 [4][4096][128]
static constexpr size_t OFF_CB   = OFF_PB + 1048576;   // Cb bf16 [4][4096][128]
static constexpr size_t OFF_GP   = OFF_PB + 2097152;   // Gram partials [4][16][128][128] f32
static constexpr size_t OFF_G    = OFF_PB + 4194304;   // G [4][128][128] f32
static constexpr size_t OFF_Z    = OFF_G + 65536;      // 16KB zero scratch
// xT (bf16, 16MB) ALIASES [OFF_PB, OFF_G): dead after conv1.

__device__ __forceinline__ unsigned short f2bf(float f) {
    unsigned u = __float_as_uint(f);
    unsigned r = (u + 0x7fffu + ((u >> 16) & 1u)) >> 16;
    return (unsigned short)r;
}

__device__ __forceinline__ void gload_lds16(const void* g, void* l) {
    __builtin_amdgcn_global_load_lds((const __attribute__((address_space(1))) void*)g,
                                     (__attribute__((address_space(3))) void*)l, 16, 0, 0);
}

// ---------------- x (fp32 NCHW) -> xT (bf16 [b][h][w][c]) ----------------
__global__ __launch_bounds__(256) void x_transpose(const float* __restrict__ x,
                                                   unsigned short* __restrict__ xT)
{
    const int h = blockIdx.x, b = blockIdx.y, cb0 = blockIdx.z * 128;
    __shared__ float tile[64][129];
    const int t = threadIdx.x;
    for (int i = t; i < 8192; i += 256) {
        int c = i >> 6, w = i & 63;
        tile[w][c] = x[(((size_t)(b * 512 + cb0 + c) * 64) + h) * 64 + w];
    }
    __syncthreads();
    for (int i = t; i < 8192; i += 256) {
        int w = i >> 7, c = i & 127;
        xT[(((size_t)(b * 64 + h) * 64) + w) * 512 + cb0 + c] = f2bf(tile[w][c]);
    }
}

// ---------------- fold BN into conv weights, bf16, staged layout (generic) ------
__global__ void prep_conv_mfma(const float* __restrict__ w, const float* __restrict__ g,
                               const float* __restrict__ bb, const float* __restrict__ m,
                               const float* __restrict__ v, unsigned short* __restrict__ wb2,
                               float* __restrict__ bias, int cin, int cout)
{
    int idx = blockIdx.x * 256 + threadIdx.x;
    if (idx < cout) {
        float sc = g[idx] * rsqrtf(v[idx] + EPSBN);
        bias[idx] = bb[idx] - m[idx] * sc;
    }
    const int cin9 = cin * 9;
    if (idx >= cout * cin9) return;
    int oc = idx / cin9;
    int rem = idx - oc * cin9;
    int c = rem / 9;
    int tap = rem - c * 9;
    int kh = tap / 3, kw = tap - kh * 3;
    float sc = g[oc] * rsqrtf(v[oc] + EPSBN);
    float val = w[idx] * sc;
    int u = (oc << 2) + (((c >> 3) & 3) ^ ((oc >> 1) & 3));
    int ncb = cin >> 5;
    size_t dst = (((size_t)(kh * ncb + (c >> 5)) * 3 + kw) * ((size_t)cout << 2) + u) * 8 + (c & 7);
    wb2[dst] = f2bf(val);
}

// ---------------- conv1 (512->128, 3x3) via bf16 MFMA implicit GEMM ----------------
__global__ __launch_bounds__(256) void conv1_mfma(
    const unsigned short* __restrict__ xT,
    const unsigned short* __restrict__ wb2p, const unsigned short* __restrict__ wb2c,
    const float* __restrict__ b1p, const float* __restrict__ b1c,
    float* __restrict__ yp, float* __restrict__ yc,
    const unsigned short* __restrict__ zbuf)
{
    const int b = blockIdx.x >> 5;
    const int h0 = (blockIdx.x & 31) * 2;
    const bool isC = (blockIdx.y >> 1) != 0;
    const int ohalf = blockIdx.y & 1;
    const int obase = ohalf << 6;
    const unsigned short* __restrict__ wb2 = isC ? wb2c : wb2p;
    const float* __restrict__ bias = isC ? b1c : b1p;
    float* __restrict__ y = isC ? yc : yp;

    const int t = threadIdx.x;
    const int wid = t >> 6, lane = t & 63;
    const int lhi = lane >> 4, llo = lane & 15;

    __shared__ __align__(16) unsigned short lds_x[8192];
    __shared__ __align__(16) unsigned short lds_w[6144];

    f32x4 acc[4][2];
#pragma unroll
    for (int i = 0; i < 4; ++i)
#pragma unroll
        for (int j = 0; j < 2; ++j) acc[i][j] = (f32x4)0.0f;

    for (int cc = 0; cc < 16; ++cc) {
        const int cb = cc * 32;
        __syncthreads();
        for (int i = wid; i < 16; i += 4) {
            const int u = (i << 6) + lane;
            const int row = u >> 8;
            const int col = (u >> 2) & 63;
            const int g2 = (u & 3) ^ ((col >> 1) & 3);
            const int xrow = h0 - 1 + row;
            const unsigned short* src = ((unsigned)xrow < 64u)
                ? xT + (((size_t)((b << 6) + xrow) << 6) + col) * 512 + cb + (g2 << 3)
                : zbuf;
            gload_lds16(src, &lds_x[(size_t)i << 9]);
        }
        {
            const unsigned short* ws = wb2 + ((size_t)(cc * 3) * 512 + (ohalf << 8)) * 8;
            for (int i = wid; i < 12; i += 4) {
                const int kw = i >> 2, seg = i & 3;
                gload_lds16(ws + ((size_t)(kw * 512 + (seg << 6) + lane) << 3),
                            &lds_w[(size_t)i << 9]);
            }
        }
        for (int kh = 0; kh < 3; ++kh) {
            if (kh) {
                __syncthreads();
                const unsigned short* ws = wb2 + ((size_t)((kh * 16 + cc) * 3) * 512 + (ohalf << 8)) * 8;
                for (int i = wid; i < 12; i += 4) {
                    const int kw = i >> 2, seg = i & 3;
                    gload_lds16(ws + ((size_t)(kw * 512 + (seg << 6) + lane) << 3),
                                &lds_w[(size_t)i << 9]);
                }
            }
            __syncthreads();
#pragma unroll
            for (int kw = 0; kw < 3; ++kw) {
                bf16x8 afr[4];
#pragma unroll
                for (int mf = 0; mf < 4; ++mf) {
                    const int ocl = (mf << 4) + llo;
                    const int un = (kw << 8) + (ocl << 2) + (lhi ^ ((ocl >> 1) & 3));
                    afr[mf] = *(const bf16x8*)&lds_w[un << 3];
                }
                bf16x8 bfr[2];
#pragma unroll
                for (int nf = 0; nf < 2; ++nf) {
                    const int px = (wid << 5) + (nf << 4) + llo;
                    const int orow = px >> 6;
                    const int wc = (px & 63) + kw - 1;
                    const bool inb = (unsigned)wc < 64u;
                    const int wcc = inb ? wc : 0;
                    const int un = (((orow + kh) << 6) + wcc) * 4 + (lhi ^ ((wcc >> 1) & 3));
                    short8v raw = *(const short8v*)&lds_x[un << 3];
                    short8v zz = {};
                    if (!inb) raw = zz;
                    bfr[nf] = __builtin_bit_cast(bf16x8, raw);
                }
#pragma unroll
                for (int mf = 0; mf < 4; ++mf)
#pragma unroll
                    for (int nf = 0; nf < 2; ++nf)
                        acc[mf][nf] = __builtin_amdgcn_mfma_f32_16x16x32_bf16(
                            afr[mf], bfr[nf], acc[mf][nf], 0, 0, 0);
            }
        }
    }

#pragma unroll
    for (int mf = 0; mf < 4; ++mf) {
#pragma unroll
        for (int r = 0; r < 4; ++r) {
            const int oc = obase + (mf << 4) + (lhi << 2) + r;
            const float bv = bias[oc];
#pragma unroll
            for (int nf = 0; nf < 2; ++nf) {
                const int px = (wid << 5) + (nf << 4) + llo;
                const int hout = h0 + (px >> 6);
                const int colw = px & 63;
                float* dst = y + (((size_t)(b * 128 + oc) << 6) + hout) * 64;
                dst[colw] = fmaxf(acc[mf][nf][r] + bv, 0.f);
            }
        }
    }
}

// ---------------- conv2 pair (128->32 x2, 3x3) fused MFMA ----------------
__global__ __launch_bounds__(256) void conv2_mfma(
    const unsigned short* __restrict__ Pb, const unsigned short* __restrict__ Cb,
    const unsigned short* __restrict__ wbp, const unsigned short* __restrict__ wbc,
    const float* __restrict__ b2p, const float* __restrict__ b2c,
    float* __restrict__ out, const unsigned short* __restrict__ zbuf)
{
    const int b = blockIdx.x >> 5;
    const int h0 = (blockIdx.x & 31) * 2;
    const int t = threadIdx.x;
    const int wid = t >> 6, lane = t & 63;
    const int lhi = lane >> 4, llo = lane & 15;

    __shared__ __align__(16) unsigned short xP[8192];
    __shared__ __align__(16) unsigned short xC[8192];
    __shared__ __align__(16) unsigned short wbuf[2][3072];

    f32x4 accP[2][2], accC[2][2];
#pragma unroll
    for (int i = 0; i < 2; ++i)
#pragma unroll
        for (int j = 0; j < 2; ++j) { accP[i][j] = (f32x4)0.0f; accC[i][j] = (f32x4)0.0f; }

    for (int cc = 0; cc < 4; ++cc) {
        const int cb = cc * 32;
        __syncthreads();
        for (int i = wid; i < 16; i += 4) {
            const int u = (i << 6) + lane;
            const int row = u >> 8;
            const int col = (u >> 2) & 63;
            const int g2 = (u & 3) ^ ((col >> 1) & 3);
            const int xrow = h0 - 1 + row;
            const bool inb = (unsigned)xrow < 64u;
            const size_t off = ((((size_t)((b << 6) + (inb ? xrow : 0)) << 6) + col) << 7) + cb + (g2 << 3);
            gload_lds16(inb ? (Pb + off) : zbuf, &xP[(size_t)i << 9]);
            gload_lds16(inb ? (Cb + off) : zbuf, &xC[(size_t)i << 9]);
        }
        {
            const size_t wb0 = (size_t)(cc * 3) * 1024;
            for (int i = wid; i < 12; i += 4) {
                const int cv = (i >= 6);
                const int ii = i - cv * 6;
                const unsigned short* ws = (cv ? wbc : wbp) + wb0;
                gload_lds16(ws + ((ii << 9) + (lane << 3)), &wbuf[cv][(size_t)ii << 9]);
            }
        }
        for (int kh = 0; kh < 3; ++kh) {
            if (kh) {
                __syncthreads();
                const size_t wb0 = (size_t)((kh * 4 + cc) * 3) * 1024;
                for (int i = wid; i < 12; i += 4) {
                    const int cv = (i >= 6);
                    const int ii = i - cv * 6;
                    const unsigned short* ws = (cv ? wbc : wbp) + wb0;
                    gload_lds16(ws + ((ii << 9) + (lane << 3)), &wbuf[cv][(size_t)ii << 9]);
                }
            }
            __syncthreads();
#pragma unroll
            for (int kw = 0; kw < 3; ++kw) {
                bf16x8 afrP[2], afrC[2];
#pragma unroll
                for (int mf = 0; mf < 2; ++mf) {
                    const int ocl = (mf << 4) + llo;
                    const int un = (kw << 7) + (ocl << 2) + (lhi ^ ((ocl >> 1) & 3));
                    afrP[mf] = *(const bf16x8*)&wbuf[0][un << 3];
                    afrC[mf] = *(const bf16x8*)&wbuf[1][un << 3];
                }
                bf16x8 bfrP[2], bfrC[2];
#pragma unroll
                for (int nf = 0; nf < 2; ++nf) {
                    const int px = (wid << 5) + (nf << 4) + llo;
                    const int orow = px >> 6;
                    const int wc = (px & 63) + kw - 1;
                    const bool inb = (unsigned)wc < 64u;
                    const int wcc = inb ? wc : 0;
                    const int un = (((orow + kh) << 6) + wcc) * 4 + (lhi ^ ((wcc >> 1) & 3));
                    short8v rawP = *(const short8v*)&xP[un << 3];
                    short8v rawC = *(const short8v*)&xC[un << 3];
                    short8v zz = {};
                    if (!inb) { rawP = zz; rawC = zz; }
                    bfrP[nf] = __builtin_bit_cast(bf16x8, rawP);
                    bfrC[nf] = __builtin_bit_cast(bf16x8, rawC);
                }
#pragma unroll
                for (int mf = 0; mf < 2; ++mf)
#pragma unroll
                    for (int nf = 0; nf < 2; ++nf) {
                        accP[mf][nf] = __builtin_amdgcn_mfma_f32_16x16x32_bf16(
                            afrP[mf], bfrP[nf], accP[mf][nf], 0, 0, 0);
                        accC[mf][nf] = __builtin_amdgcn_mfma_f32_16x16x32_bf16(
                            afrC[mf], bfrC[nf], accC[mf][nf], 0, 0, 0);
                    }
            }
        }
    }

#pragma unroll
    for (int mf = 0; mf < 2; ++mf) {
#pragma unroll
        for (int r = 0; r < 4; ++r) {
            const int oc = (mf << 4) + (lhi << 2) + r;
            const float bp = b2p[oc], bc = b2c[oc];
#pragma unroll
            for (int nf = 0; nf < 2; ++nf) {
                const int px = (wid << 5) + (nf << 4) + llo;
                const int hout = h0 + (px >> 6);
                const int colw = px & 63;
                const float val = fmaxf(accP[mf][nf][r] + bp, 0.f)
                                + fmaxf(accC[mf][nf][r] + bc, 0.f);
                out[(((size_t)(b * 32 + oc)) << 12) + (hout << 6) + colw] = val;
            }
        }
    }
}

// ---------------- PAM projections: q(scaled by log2e),k -> bf16 [n][32]; d -> VF ----
__global__ __launch_bounds__(256) void pam_proj(
    const float* __restrict__ yp,
    const float* __restrict__ wb, const float* __restrict__ bbq,
    const float* __restrict__ wc, const float* __restrict__ bck,
    const float* __restrict__ wd, const float* __restrict__ bdv,
    unsigned short* __restrict__ Qb, unsigned short* __restrict__ Kb,
    unsigned short* __restrict__ VFo)
{
    const int b = blockIdx.y;
    const int n0 = blockIdx.x * 64;
    const int t = threadIdx.x;
    const int px = t & 63;
    const int og = t >> 6;

    __shared__ __align__(16) float lds_y[64][64];
    __shared__ __align__(16) float lds_w[64][164];

    float acc[10][4];
#pragma unroll
    for (int s = 0; s < 10; ++s) { acc[s][0] = acc[s][1] = acc[s][2] = acc[s][3] = 0.f; }

    for (int cb = 0; cb < 128; cb += 64) {
        for (int i = t; i < 4096; i += 256) {
            int c = i >> 6, p = i & 63;
            lds_y[c][p] = yp[(((size_t)b * 128 + cb + c) << 12) + n0 + p];
        }
        for (int i = t; i < 160 * 64; i += 256) {
            int c = i & 63, o = i >> 6;
            const float* src = (o < 16) ? (wb + o * 128)
                             : (o < 32) ? (wc + (o - 16) * 128)
                                        : (wd + (o - 32) * 128);
            lds_w[c][o] = src[cb + c];
        }
        __syncthreads();
        for (int c = 0; c < 64; ++c) {
            float yv = lds_y[c][px];
#pragma unroll
            for (int s = 0; s < 10; ++s) {
                const float4 w4 = *(const float4*)&lds_w[c][s * 16 + og * 4];
                acc[s][0] += w4.x * yv; acc[s][1] += w4.y * yv;
                acc[s][2] += w4.z * yv; acc[s][3] += w4.w * yv;
            }
        }
        __syncthreads();
    }
    const int n = n0 + px;
    const size_t qkrow = ((size_t)(b << 12) + n) << 5;
#pragma unroll
    for (int s = 0; s < 10; ++s) {
        const float* bsrc = (s == 0) ? (bbq + og * 4)
                          : (s == 1) ? (bck + og * 4)
                                     : (bdv + (s - 2) * 16 + og * 4);
        const float4 bv4 = *(const float4*)bsrc;
        float v0 = acc[s][0] + bv4.x, v1 = acc[s][1] + bv4.y;
        float v2 = acc[s][2] + bv4.z, v3 = acc[s][3] + bv4.w;
        if (s == 0) { v0 *= LOG2E; v1 *= LOG2E; v2 *= LOG2E; v3 *= LOG2E; }
        if (s < 2) {
            unsigned short* dst = (s == 0) ? Qb : Kb;
            uint2 pk2;
            pk2.x = (unsigned)f2bf(v0) | ((unsigned)f2bf(v1) << 16);
            pk2.y = (unsigned)f2bf(v2) | ((unsigned)f2bf(v3) << 16);
            *(uint2*)&dst[qkrow + (og << 2)] = pk2;
            uint2 z2; z2.x = 0u; z2.y = 0u;
            *(uint2*)&dst[qkrow + 16 + (og << 2)] = z2;
        } else {
            const int cf = s - 2;
            const size_t blk = ((size_t)(b * 128 + (n >> 5)) * 8 + cf) << 9;
            const int gl = ((n >> 2) & 3) << 4;
            const int j = (n & 3) | (((n >> 4) & 1) << 2);
            const float vv[4] = {v0, v1, v2, v3};
#pragma unroll
            for (int u = 0; u < 4; ++u)
                VFo[blk + ((size_t)((gl | (og * 4 + u)) << 3)) + j] = f2bf(vv[u]);
        }
    }
}

// ---------------- PAM fused attention: 2 q-frags/wave, 4 waves, online softmax ----
// grid (128, B), 256 thr = 4 waves; wave kq owns keys [kq*1024, kq*1024+1024).
__global__ __launch_bounds__(256, 2) void pam_attn_mfma(
    const unsigned short* __restrict__ Qb, const unsigned short* __restrict__ Kb,
    const unsigned short* __restrict__ VF, const float* __restrict__ yp,
    const float* __restrict__ alpha_p, unsigned short* __restrict__ Pb)
{
    const int b = blockIdx.y;
    const int q0 = blockIdx.x * 32;
    const int t = threadIdx.x;
    const int kq = t >> 6, lane = t & 63;
    const int g = lane >> 4, qi = lane & 15;

    __shared__ float smO[2][64][33];          // cross-wave O accumulator
    __shared__ float combM[4][16];
    __shared__ float combL0[4][16];
    __shared__ float combL1[4][16];
    __shared__ unsigned short smP[32 * 128];

    for (int i = t; i < 2 * 64 * 33; i += 256) ((float*)smO)[i] = 0.f;

    const bf16x8 qf0 = *(const bf16x8*)&Qb[(((size_t)(b << 12) + q0 + qi) << 5) + (g << 3)];
    const bf16x8 qf1 = *(const bf16x8*)&Qb[(((size_t)(b << 12) + q0 + 16 + qi) << 5) + (g << 3)];
    const unsigned short* __restrict__ Kbase = Kb + ((size_t)b << 17);
    const unsigned short* __restrict__ VFb = VF + ((size_t)b << 19);

    bf16x8 ones;
#pragma unroll
    for (int j = 0; j < 8; ++j) ones[j] = (__bf16)1.0f;

    f32x4 accO0[8], accO1[8];
#pragma unroll
    for (int cf = 0; cf < 8; ++cf) { accO0[cf] = (f32x4)0.0f; accO1[cf] = (f32x4)0.0f; }
    f32x4 accL0 = (f32x4)0.0f, accL1 = (f32x4)0.0f;
    float m = -3.0e38f;

    const int ktbase = kq << 5;               // 32 key-tiles (of 32 keys) per quarter
    #define KF(kt, half) (*(const bf16x8*)&Kbase[((size_t)((((kt) << 5) + (half)) + qi) << 5) + (g << 3)])
    bf16x8 kE0 = KF(ktbase, 0), kO0 = KF(ktbase, 16);
    bf16x8 kE1 = KF(ktbase + 1, 0), kO1 = KF(ktbase + 1, 16);

    for (int g2 = 0; g2 < 16; ++g2) {
        const int kt0 = ktbase + (g2 << 1);
        const unsigned short* vt0 = VFb + ((size_t)kt0 << 12) + (lane << 3);
        const unsigned short* vt1 = vt0 + 4096;
        // VF kt0 early
        bf16x8 va0 = *(const bf16x8*)&vt0[0],    va1 = *(const bf16x8*)&vt0[512];
        bf16x8 va2 = *(const bf16x8*)&vt0[1024], va3 = *(const bf16x8*)&vt0[1536];
        bf16x8 va4 = *(const bf16x8*)&vt0[2048], va5 = *(const bf16x8*)&vt0[2560];
        bf16x8 va6 = *(const bf16x8*)&vt0[3072], va7 = *(const bf16x8*)&vt0[3584];
        f32x4 z = {};
        f32x4 sE0a = __builtin_amdgcn_mfma_f32_16x16x32_bf16(kE0, qf0, z, 0, 0, 0);
        f32x4 sO0a = __builtin_amdgcn_mfma_f32_16x16x32_bf16(kO0, qf0, z, 0, 0, 0);
        f32x4 sE0b = __builtin_amdgcn_mfma_f32_16x16x32_bf16(kE0, qf1, z, 0, 0, 0);
        f32x4 sO0b = __builtin_amdgcn_mfma_f32_16x16x32_bf16(kO0, qf1, z, 0, 0, 0);
        f32x4 sE1a = __builtin_amdgcn_mfma_f32_16x16x32_bf16(kE1, qf0, z, 0, 0, 0);
        f32x4 sO1a = __builtin_amdgcn_mfma_f32_16x16x32_bf16(kO1, qf0, z, 0, 0, 0);
        f32x4 sE1b = __builtin_amdgcn_mfma_f32_16x16x32_bf16(kE1, qf1, z, 0, 0, 0);
        f32x4 sO1b = __builtin_amdgcn_mfma_f32_16x16x32_bf16(kO1, qf1, z, 0, 0, 0);
        // prefetch next pair of K tiles
        const int ktn = (g2 < 15) ? kt0 + 2 : kt0;
        bf16x8 nkE0 = KF(ktn, 0), nkO0 = KF(ktn, 16);
        bf16x8 nkE1 = KF(ktn + 1, 0), nkO1 = KF(ktn + 1, 16);
        // single max-check per 64 keys x 2 q-groups
        float pm = -3.0e38f;
#pragma unroll
        for (int r = 0; r < 4; ++r) {
            pm = fmaxf(pm, fmaxf(fmaxf(sE0a[r], sO0a[r]), fmaxf(sE0b[r], sO0b[r])));
            pm = fmaxf(pm, fmaxf(fmaxf(sE1a[r], sO1a[r]), fmaxf(sE1b[r], sO1b[r])));
        }
        pm = fmaxf(pm, __shfl_xor(pm, 16));
        pm = fmaxf(pm, __shfl_xor(pm, 32));
        if (!__all(pm <= m + 8.f)) {          // defer-max (log2 units)
            const float nm = fmaxf(m, pm);
            const float fac = exp2f(m - nm);
#pragma unroll
            for (int cf = 0; cf < 8; ++cf) { accO0[cf] *= fac; accO1[cf] *= fac; }
            accL0 *= fac; accL1 *= fac;
            m = nm;
        }
        bf16x8 pb0a, pb0b, pb1a, pb1b;
#pragma unroll
        for (int r = 0; r < 4; ++r) {
            pb0a[r]     = (__bf16)exp2f(sE0a[r] - m);
            pb0a[4 + r] = (__bf16)exp2f(sO0a[r] - m);
            pb0b[r]     = (__bf16)exp2f(sE0b[r] - m);
            pb0b[4 + r] = (__bf16)exp2f(sO0b[r] - m);
            pb1a[r]     = (__bf16)exp2f(sE1a[r] - m);
            pb1a[4 + r] = (__bf16)exp2f(sO1a[r] - m);
            pb1b[r]     = (__bf16)exp2f(sE1b[r] - m);
            pb1b[4 + r] = (__bf16)exp2f(sO1b[r] - m);
        }
        // PV kt0: each VF fragment feeds both q-groups
        accO0[0] = __builtin_amdgcn_mfma_f32_16x16x32_bf16(va0, pb0a, accO0[0], 0, 0, 0);
        accO1[0] = __builtin_amdgcn_mfma_f32_16x16x32_bf16(va0, pb0b, accO1[0], 0, 0, 0);
        accO0[1] = __builtin_amdgcn_mfma_f32_16x16x32_bf16(va1, pb0a, accO0[1], 0, 0, 0);
        accO1[1] = __builtin_amdgcn_mfma_f32_16x16x32_bf16(va1, pb0b, accO1[1], 0, 0, 0);
        accO0[2] = __builtin_amdgcn_mfma_f32_16x16x32_bf16(va2, pb0a, accO0[2], 0, 0, 0);
        accO1[2] = __builtin_amdgcn_mfma_f32_16x16x32_bf16(va2, pb0b, accO1[2], 0, 0, 0);
        accO0[3] = __builtin_amdgcn_mfma_f32_16x16x32_bf16(va3, pb0a, accO0[3], 0, 0, 0);
        accO1[3] = __builtin_amdgcn_mfma_f32_16x16x32_bf16(va3, pb0b, accO1[3], 0, 0, 0);
        // VF kt1 loads overlap kt0 tail
        bf16x8 vb0 = *(const bf16x8*)&vt1[0],    vb1 = *(const bf16x8*)&vt1[512];
        bf16x8 vb2 = *(const bf16x8*)&vt1[1024], vb3 = *(const bf16x8*)&vt1[1536];
        bf16x8 vb4 = *(const bf16x8*)&vt1[2048], vb5 = *(const bf16x8*)&vt1[2560];
        bf16x8 vb6 = *(const bf16x8*)&vt1[3072], vb7 = *(const bf16x8*)&vt1[3584];
        accO0[4] = __builtin_amdgcn_mfma_f32_16x16x32_bf16(va4, pb0a, accO0[4], 0, 0, 0);
        accO1[4] = __builtin_amdgcn_mfma_f32_16x16x32_bf16(va4, pb0b, accO1[4], 0, 0, 0);
        accO0[5] = __builtin_amdgcn_mfma_f32_16x16x32_bf16(va5, pb0a, accO0[5], 0, 0, 0);
        accO1[5] = __builtin_amdgcn_mfma_f32_16x16x32_bf16(va5, pb0b, accO1[5], 0, 0, 0);
        accO0[6] = __builtin_amdgcn_mfma_f32_16x16x32_bf16(va6, pb0a, accO0[6], 0, 0, 0);
        accO1[6] = __builtin_amdgcn_mfma_f32_16x16x32_bf16(va6, pb0b, accO1[6], 0, 0, 0);
        accO0[7] = __builtin_amdgcn_mfma_f32_16x16x32_bf16(va7, pb0a, accO0[7], 0, 0, 0);
        accO1[7] = __builtin_amdgcn_mfma_f32_16x16x32_bf16(va7, pb0b, accO1[7], 0, 0, 0);
        accL0    = __builtin_amdgcn_mfma_f32_16x16x32_bf16(ones, pb0a, accL0, 0, 0, 0);
        accL1    = __builtin_amdgcn_mfma_f32_16x16x32_bf16(ones, pb0b, accL1, 0, 0, 0);
        // PV kt1
        accO0[0] = __builtin_amdgcn_mfma_f32_16x16x32_bf16(vb0, pb1a, accO0[0], 0, 0, 0);
        accO1[0] = __builtin_amdgcn_mfma_f32_16x16x32_bf16(vb0, pb1b, accO1[0], 0, 0, 0);
        accO0[1] = __builtin_amdgcn_mfma_f32_16x16x32_bf16(vb1, pb1a, accO0[1], 0, 0, 0);
        accO1[1] = __builtin_amdgcn_mfma_f32_16x16x32_bf16(vb1, pb1b, accO1[1], 0, 0, 0);
        accO0[2] = __builtin_amdgcn_mfma_f32_16x16x32_bf16(vb2, pb1a, accO0[2], 0, 0, 0);
        accO1[2] = __builtin_amdgcn_mfma_f32_16x16x32_bf16(vb2, pb1b, accO1[2], 0, 0, 0);
        accO0[3] = __builtin_amdgcn_mfma_f32_16x16x32_bf16(vb3, pb1a, accO0[3], 0, 0, 0);
        accO1[3] = __builtin_amdgcn_mfma_f32_16x16x32_bf16(vb3, pb1b, accO1[3], 0, 0, 0);
        accO0[4] = __builtin_amdgcn_mfma_f32_16x16x32_bf16(vb4, pb1a, accO0[4], 0, 0, 0);
        accO1[4] = __builtin_amdgcn_mfma_f32_16x16x32_bf16(vb4, pb1b, accO1[4], 0, 0, 0);
        accO0[5] = __builtin_amdgcn_mfma_f32_16x16x32_bf16(vb5, pb1a, accO0[5], 0, 0, 0);
        accO1[5] = __builtin_amdgcn_mfma_f32_16x16x32_bf16(vb5, pb1b, accO1[5], 0, 0, 0);
        accO0[6] = __builtin_amdgcn_mfma_f32_16x16x32_bf16(vb6, pb1a, accO0[6], 0, 0, 0);
        accO1[6] = __builtin_amdgcn_mfma_f32_16x16x32_bf16(vb6, pb1b, accO1[6], 0, 0, 0);
        accO0[7] = __builtin_amdgcn_mfma_f32_16x16x32_bf16(vb7, pb1a, accO0[7], 0, 0, 0);
        accO1[7] = __builtin_amdgcn_mfma_f32_16x16x32_bf16(vb7, pb1b, accO1[7], 0, 0, 0);
        accL0    = __builtin_amdgcn_mfma_f32_16x16x32_bf16(ones, pb1a, accL0, 0, 0, 0);
        accL1    = __builtin_amdgcn_mfma_f32_16x16x32_bf16(ones, pb1b, accL1, 0, 0, 0);
        kE0 = nkE0; kO0 = nkO0; kE1 = nkE1; kO1 = nkO1;
    }
    #undef KF

    if (lane < 16) {
        combM[kq][lane] = m;
        combL0[kq][lane] = accL0[0];
        combL1[kq][lane] = accL1[0];
    }
    __syncthreads();

    const float M = fmaxf(fmaxf(combM[0][qi], combM[1][qi]),
                          fmaxf(combM[2][qi], combM[3][qi]));
    const float fac = exp2f(m - M);
#pragma unroll
    for (int cf = 0; cf < 8; ++cf) { accO0[cf] *= fac; accO1[cf] *= fac; }

    if (kq != 0) {
#pragma unroll
        for (int cf = 0; cf < 8; ++cf)
#pragma unroll
            for (int r = 0; r < 4; ++r) {
                atomicAdd(&smO[0][lane][cf * 4 + r], accO0[cf][r]);
                atomicAdd(&smO[1][lane][cf * 4 + r], accO1[cf][r]);
            }
    }
    __syncthreads();
    if (kq == 0) {
        float l0 = 0.f, l1 = 0.f;
#pragma unroll
        for (int k2 = 0; k2 < 4; ++k2) {
            const float e = exp2f(combM[k2][qi] - M);
            l0 += e * combL0[k2][qi];
            l1 += e * combL1[k2][qi];
        }
        const float al = alpha_p[0];
        const float sc0 = al / l0, sc1 = al / l1;
#pragma unroll
        for (int cf = 0; cf < 8; ++cf) {
#pragma unroll
            for (int r = 0; r < 4; ++r) {
                const int ch = cf * 16 + (g << 2) + r;
                const size_t o0 = (((size_t)(b * 128 + ch)) << 12) + q0 + qi;
                const float v0 = (accO0[cf][r] + smO[0][lane][cf * 4 + r]) * sc0 + yp[o0];
                const float v1 = (accO1[cf][r] + smO[1][lane][cf * 4 + r]) * sc1 + yp[o0 + 16];
                smP[qi * 128 + ch] = f2bf(v0);
                smP[(16 + qi) * 128 + ch] = f2bf(v1);
            }
        }
    }
    __syncthreads();
    unsigned* Pb32 = (unsigned*)Pb;
    const unsigned* sm32 = (const unsigned*)smP;
    for (int i = t; i < 2048; i += 256) {
        const int row = i >> 6, u = i & 63;
        Pb32[((size_t)(b << 12) + q0 + row) * 64 + u] = sm32[i];
    }
}

// ---------------- CAM Gram via MFMA, bf16 hi/lo split (fp32-accurate) ----------
__global__ __launch_bounds__(256) void cam_gram_mfma(const float* __restrict__ yc,
                                                     float* __restrict__ GP)
{
    const int kb = blockIdx.x, b = blockIdx.y;
    const int t = threadIdx.x;
    const int wid = t >> 6, lane = t & 63;
    const int lhi = lane >> 4, llo = lane & 15;
    const int mr = (wid & 1) << 6, nr = (wid >> 1) << 6;
    const float* __restrict__ Y = yc + ((size_t)b << 19);

    f32x4 acc[4][4];
#pragma unroll
    for (int i = 0; i < 4; ++i)
#pragma unroll
        for (int j = 0; j < 4; ++j) acc[i][j] = (f32x4)0.0f;

    for (int ks = 0; ks < 8; ++ks) {
        const int n0 = (kb << 8) + (ks << 5) + (lhi << 3);
        bf16x8 ah[4], al[4], bh[4], bl[4];
#pragma unroll
        for (int mf = 0; mf < 4; ++mf) {
            const int row = mr + (mf << 4) + llo;
            const float* p = &Y[((size_t)row << 12) + n0];
            const float4 v0 = *(const float4*)p;
            const float4 v1 = *(const float4*)(p + 4);
            const float vv[8] = {v0.x, v0.y, v0.z, v0.w, v1.x, v1.y, v1.z, v1.w};
#pragma unroll
            for (int j = 0; j < 8; ++j) {
                const __bf16 h = (__bf16)vv[j];
                ah[mf][j] = h;
                al[mf][j] = (__bf16)(vv[j] - (float)h);
            }
        }
#pragma unroll
        for (int nf = 0; nf < 4; ++nf) {
            const int row = nr + (nf << 4) + llo;
            const float* p = &Y[((size_t)row << 12) + n0];
            const float4 v0 = *(const float4*)p;
            const float4 v1 = *(const float4*)(p + 4);
            const float vv[8] = {v0.x, v0.y, v0.z, v0.w, v1.x, v1.y, v1.z, v1.w};
#pragma unroll
            for (int j = 0; j < 8; ++j) {
                const __bf16 h = (__bf16)vv[j];
                bh[nf][j] = h;
                bl[nf][j] = (__bf16)(vv[j] - (float)h);
            }
        }
#pragma unroll
        for (int mf = 0; mf < 4; ++mf)
#pragma unroll
            for (int nf = 0; nf < 4; ++nf) {
                acc[mf][nf] = __builtin_amdgcn_mfma_f32_16x16x32_bf16(ah[mf], bh[nf], acc[mf][nf], 0, 0, 0);
                acc[mf][nf] = __builtin_amdgcn_mfma_f32_16x16x32_bf16(ah[mf], bl[nf], acc[mf][nf], 0, 0, 0);
                acc[mf][nf] = __builtin_amdgcn_mfma_f32_16x16x32_bf16(al[mf], bh[nf], acc[mf][nf], 0, 0, 0);
            }
    }
    const size_t base = ((size_t)((b << 4) + kb) << 14);
#pragma unroll
    for (int mf = 0; mf < 4; ++mf)
#pragma unroll
        for (int nf = 0; nf < 4; ++nf)
#pragma unroll
            for (int r = 0; r < 4; ++r) {
                const int c = mr + (mf << 4) + (lhi << 2) + r;
                const int d = nr + (nf << 4) + llo;
                GP[base + ((size_t)c << 7) + d] = acc[mf][nf][r];
            }
}

__global__ __launch_bounds__(256) void cam_gram_reduce(const float* __restrict__ GP,
                                                       float* __restrict__ G)
{
    const int b = blockIdx.y;
    const int i0 = blockIdx.x * 1024 + threadIdx.x * 4;
    float4 s = make_float4(0.f, 0.f, 0.f, 0.f);
#pragma unroll
    for (int kb = 0; kb < 16; ++kb) {
        const float4 v = *(const float4*)&GP[((size_t)((b << 4) + kb) << 14) + i0];
        s.x += v.x; s.y += v.y; s.z += v.z; s.w += v.w;
    }
    *(float4*)&G[((size_t)b << 14) + i0] = s;
}

// ---------------- CAM: softmax + apply + beta residual -> Cb bf16 [b][n][128] ----
__global__ __launch_bounds__(256) void cam_apply(
    const float* __restrict__ G, const float* __restrict__ yc,
    const float* __restrict__ beta_p, unsigned short* __restrict__ Cb)
{
    const int b = blockIdx.y;
    const int cchunk = blockIdx.x >> 4;
    const int ns = blockIdx.x & 15;
    const int t = threadIdx.x;

    __shared__ float att_t[128][32];
    __shared__ float s_buf[128 * 64];
    __shared__ unsigned short smC[64 * 32];

    for (int i = t; i < 4096; i += 256)
        s_buf[i] = G[((size_t)b << 14) + (size_t)cchunk * 32 * 128 + i];
    __syncthreads();
    {
        const int r = t >> 3, seg = t & 7;
        float vals[16];
        float gmin = 3.0e38f;
#pragma unroll
        for (int u = 0; u < 16; ++u) {
            vals[u] = s_buf[r * 128 + seg * 16 + u];
            gmin = fminf(gmin, vals[u]);
        }
        gmin = fminf(gmin, __shfl_xor(gmin, 1));
        gmin = fminf(gmin, __shfl_xor(gmin, 2));
        gmin = fminf(gmin, __shfl_xor(gmin, 4));
        float sum = 0.f;
#pragma unroll
        for (int u = 0; u < 16; ++u) { vals[u] = __expf(gmin - vals[u]); sum += vals[u]; }
        sum += __shfl_xor(sum, 1);
        sum += __shfl_xor(sum, 2);
        sum += __shfl_xor(sum, 4);
        const float inv = 1.f / sum;
#pragma unroll
        for (int u = 0; u < 16; ++u)
            att_t[seg * 16 + u][r] = vals[u] * inv;
    }
    __syncthreads();

    const float be = beta_p[0];
    const int nc = t & 31, cgp = t >> 5;
    unsigned* Cb32 = (unsigned*)Cb;
    const unsigned* smC32 = (const unsigned*)smC;
    for (int chunk = 0; chunk < 4; ++chunk) {
        const int nb = ns * 256 + chunk * 64;
        for (int i = t; i < 8192; i += 256) {
            int d = i >> 6, nn = i & 63;
            s_buf[d * 64 + nn] = yc[(((size_t)b * 128 + d) << 12) + nb + nn];
        }
        __syncthreads();
        float a0[4] = {0, 0, 0, 0}, a1[4] = {0, 0, 0, 0};
        for (int d = 0; d < 128; ++d) {
            const float y0 = s_buf[d * 64 + nc];
            const float y1 = s_buf[d * 64 + nc + 32];
#pragma unroll
            for (int o = 0; o < 4; ++o) {
                const float wv = att_t[d][cgp * 4 + o];
                a0[o] += wv * y0; a1[o] += wv * y1;
            }
        }
#pragma unroll
        for (int o = 0; o < 4; ++o) {
            const int cl = cgp * 4 + o;
            const int c = cchunk * 32 + cl;
            smC[nc * 32 + cl]        = f2bf(be * a0[o] + s_buf[c * 64 + nc]);
            smC[(nc + 32) * 32 + cl] = f2bf(be * a1[o] + s_buf[c * 64 + nc + 32]);
        }
        __syncthreads();
        for (int i = t; i < 1024; i += 256) {
            const int row = i >> 4, u = i & 15;
            Cb32[((size_t)(b << 12) + nb + row) * 64 + (cchunk << 4) + u] = smC32[i];
        }
        __syncthreads();
    }
}

// ---------------- launcher ----------------
extern "C" void kernel_launch(void* const* d_in, const int* in_sizes, int n_in,
                              void* d_out, int out_size, void* d_ws, size_t ws_size,
                              hipStream_t stream)
{
    (void)in_sizes; (void)n_in; (void)out_size; (void)ws_size;
    const float* x    = (const float*)d_in[0];
    const float* wp1  = (const float*)d_in[1];
    const float* gp1  = (const float*)d_in[2];
    const float* bp1  = (const float*)d_in[3];
    const float* mp1  = (const float*)d_in[4];
    const float* vp1  = (const float*)d_in[5];
    const float* wc1  = (const float*)d_in[6];
    const float* gc1  = (const float*)d_in[7];
    const float* bc1  = (const float*)d_in[8];
    const float* mc1  = (const float*)d_in[9];
    const float* vc1  = (const float*)d_in[10];
    const float* pwb  = (const float*)d_in[11];
    const float* pbb  = (const float*)d_in[12];
    const float* pwc  = (const float*)d_in[13];
    const float* pbc  = (const float*)d_in[14];
    const float* pwd  = (const float*)d_in[15];
    const float* pbd  = (const float*)d_in[16];
    const float* alpha= (const float*)d_in[17];
    const float* beta = (const float*)d_in[18];
    const float* wp2  = (const float*)d_in[19];
    const float* gp2  = (const float*)d_in[20];
    const float* bp2  = (const float*)d_in[21];
    const float* mp2  = (const float*)d_in[22];
    const float* vp2  = (const float*)d_in[23];
    const float* wc2  = (const float*)d_in[24];
    const float* gc2  = (const float*)d_in[25];
    const float* bc2  = (const float*)d_in[26];
    const float* mc2  = (const float*)d_in[27];
    const float* vc2  = (const float*)d_in[28];

    float* W = (float*)d_ws;
    unsigned short* wb2p16 = (unsigned short*)(W + OFF_WB2P);
    unsigned short* wb2c16 = (unsigned short*)(W + OFF_WB2C);
    float* b1p = W + OFF_B1P;
    float* b1c = W + OFF_B1C;
    unsigned short* wt2p16 = (unsigned short*)(W + OFF_WT2P);
    unsigned short* wt2c16 = (unsigned short*)(W + OFF_WT2C);
    float* b2p = W + OFF_B2P;
    float* b2c = W + OFF_B2C;
    float* yp   = W + OFF_YP;
    float* yc   = W + OFF_YC;
    unsigned short* Qb16 = (unsigned short*)(W + OFF_Q);
    unsigned short* Kb16 = (unsigned short*)(W + OFF_K);
    unsigned short* VF16 = (unsigned short*)(W + OFF_V);
    unsigned short* Pb16 = (unsigned short*)(W + OFF_PB);
    unsigned short* Cb16 = (unsigned short*)(W + OFF_CB);
    float* GP   = W + OFF_GP;
    float* G    = W + OFF_G;
    unsigned short* xT16  = (unsigned short*)(W + OFF_PB);  // alias, dead after conv1
    unsigned short* zb16  = (unsigned short*)(W + OFF_Z);
    float* out  = (float*)d_out;

    hipMemsetAsync(zb16, 0, 4096 * sizeof(float), stream);

    x_transpose<<<dim3(64, 4, 4), 256, 0, stream>>>(x, xT16);
    prep_conv_mfma<<<2304, 256, 0, stream>>>(wp1, gp1, bp1, mp1, vp1, wb2p16, b1p, 512, 128);
    prep_conv_mfma<<<2304, 256, 0, stream>>>(wc1, gc1, bc1, mc1, vc1, wb2c16, b1c, 512, 128);
    prep_conv_mfma<<<144,  256, 0, stream>>>(wp2, gp2, bp2, mp2, vp2, wt2p16, b2p, 128, 32);
    prep_conv_mfma<<<144,  256, 0, stream>>>(wc2, gc2, bc2, mc2, vc2, wt2c16, b2c, 128, 32);

    conv1_mfma<<<dim3(128, 4), 256, 0, stream>>>(xT16, wb2p16, wb2c16, b1p, b1c, yp, yc, zb16);

    pam_proj<<<dim3(64, 4), 256, 0, stream>>>(yp, pwb, pbb, pwc, pbc, pwd, pbd, Qb16, Kb16, VF16);
    pam_attn_mfma<<<dim3(128, 4), 256, 0, stream>>>(Qb16, Kb16, VF16, yp, alpha, Pb16);

    cam_gram_mfma<<<dim3(16, 4), 256, 0, stream>>>(yc, GP);
    cam_gram_reduce<<<dim3(16, 4), 256, 0, stream>>>(GP, G);
    cam_apply<<<dim3(64, 4), 256, 0, stream>>>(G, yc, beta, Cb16);

    conv2_mfma<<<128, 256, 0, stream>>>(Pb16, Cb16, wt2p16, wt2c16, b2p, b2c, out, zb16);
}

// Round 8
// 324.127 us; speedup vs baseline: 1.0808x; 1.0808x over previous
//
#include <hip/hip_runtime.h>
#include <cstddef>
#include <cstdint>

#define EPSBN 1e-5f
#define LOG2E 1.4426950408889634f
#define M_FIX 16.0f   // fixed softmax shift (log2 units); safe for |s|log2 << 100

typedef __attribute__((ext_vector_type(8))) __bf16 bf16x8;
typedef __attribute__((ext_vector_type(8))) short short8v;
typedef __attribute__((ext_vector_type(4))) float f32x4;

// ---------------- workspace layout (in floats) ----------------
static constexpr size_t SZ_WB2 = 294912;     // conv1 wb: 4608*128 ushorts / 2
static constexpr size_t SZ_WT2 = 36864;      // conv2 wb
static constexpr size_t SZ_Y   = 2097152;    // 4*128*4096 fp32
static constexpr size_t SZ_QK  = 262144;     // 4*4096*32 ushorts / 2

static constexpr size_t OFF_WB2P = 0;
static constexpr size_t OFF_B1P  = OFF_WB2P + SZ_WB2;
static constexpr size_t OFF_WB2C = OFF_B1P + 128;
static constexpr size_t OFF_B1C  = OFF_WB2C + SZ_WB2;
static constexpr size_t OFF_WT2P = OFF_B1C + 128;
static constexpr size_t OFF_B2P  = OFF_WT2P + SZ_WT2;
static constexpr size_t OFF_WT2C = OFF_B2P + 32;
static constexpr size_t OFF_B2C  = OFF_WT2C + SZ_WT2;
static constexpr size_t OFF_YP   = OFF_B2C + 32;
static constexpr size_t OFF_YC   = OFF_YP + SZ_Y;
static constexpr size_t OFF_Q    = OFF_YC + SZ_Y;      // Qb bf16 [4][4096][32] (pre-scaled by log2e)
static constexpr size_t OFF_K    = OFF_Q + SZ_QK;      // Kb bf16 [4][4096][32]
static constexpr size_t OFF_V    = OFF_K + SZ_QK;      // VF bf16 frag stream, 4MB
static constexpr size_t OFF_PB   = OFF_V + SZ_Y;       // Pb bf16 [4][4096][128]
static constexpr size_t OFF_CB   = OFF_PB + 1048576;   // Cb bf16 [4][4096][128]
static constexpr size_t OFF_GP   = OFF_PB + 2097152;   // Gram partials [4][16][128][128] f32
static constexpr size_t OFF_G    = OFF_PB + 4194304;   // G [4][128][128] f32
static constexpr size_t OFF_Z    = OFF_G + 65536;      // 16KB zero scratch
// xT (bf16, 16MB) ALIASES [OFF_PB, OFF_G): dead after conv1.

__device__ __forceinline__ unsigned short f2bf(float f) {
    unsigned u = __float_as_uint(f);
    unsigned r = (u + 0x7fffu + ((u >> 16) & 1u)) >> 16;
    return (unsigned short)r;
}

__device__ __forceinline__ void gload_lds16(const void* g, void* l) {
    __builtin_amdgcn_global_load_lds((const __attribute__((address_space(1))) void*)g,
                                     (__attribute__((address_space(3))) void*)l, 16, 0, 0);
}

// ---------------- x (fp32 NCHW) -> xT (bf16 [b][h][w][c]) ----------------
__global__ __launch_bounds__(256) void x_transpose(const float* __restrict__ x,
                                                   unsigned short* __restrict__ xT)
{
    const int h = blockIdx.x, b = blockIdx.y, cb0 = blockIdx.z * 128;
    __shared__ float tile[64][129];
    const int t = threadIdx.x;
    for (int i = t; i < 8192; i += 256) {
        int c = i >> 6, w = i & 63;
        tile[w][c] = x[(((size_t)(b * 512 + cb0 + c) * 64) + h) * 64 + w];
    }
    __syncthreads();
    for (int i = t; i < 8192; i += 256) {
        int w = i >> 7, c = i & 127;
        xT[(((size_t)(b * 64 + h) * 64) + w) * 512 + cb0 + c] = f2bf(tile[w][c]);
    }
}

// ---------------- fold BN into conv weights, bf16, staged layout (pair) ------
// grid.y selects conv (0 = P-path, 1 = C-path).
__global__ void prep_conv_mfma(const float* __restrict__ w0, const float* __restrict__ g0,
                               const float* __restrict__ bb0, const float* __restrict__ m0,
                               const float* __restrict__ v0,
                               const float* __restrict__ w1, const float* __restrict__ g1,
                               const float* __restrict__ bb1, const float* __restrict__ m1,
                               const float* __restrict__ v1,
                               unsigned short* __restrict__ wb2_0, unsigned short* __restrict__ wb2_1,
                               float* __restrict__ bias0, float* __restrict__ bias1,
                               int cin, int cout)
{
    const bool sec = blockIdx.y != 0;
    const float* __restrict__ w = sec ? w1 : w0;
    const float* __restrict__ g = sec ? g1 : g0;
    const float* __restrict__ bb = sec ? bb1 : bb0;
    const float* __restrict__ m = sec ? m1 : m0;
    const float* __restrict__ v = sec ? v1 : v0;
    unsigned short* __restrict__ wb2 = sec ? wb2_1 : wb2_0;
    float* __restrict__ bias = sec ? bias1 : bias0;

    int idx = blockIdx.x * 256 + threadIdx.x;
    if (idx < cout) {
        float sc = g[idx] * rsqrtf(v[idx] + EPSBN);
        bias[idx] = bb[idx] - m[idx] * sc;
    }
    const int cin9 = cin * 9;
    if (idx >= cout * cin9) return;
    int oc = idx / cin9;
    int rem = idx - oc * cin9;
    int c = rem / 9;
    int tap = rem - c * 9;
    int kh = tap / 3, kw = tap - kh * 3;
    float sc = g[oc] * rsqrtf(v[oc] + EPSBN);
    float val = w[idx] * sc;
    int u = (oc << 2) + (((c >> 3) & 3) ^ ((oc >> 1) & 3));
    int ncb = cin >> 5;
    size_t dst = (((size_t)(kh * ncb + (c >> 5)) * 3 + kw) * ((size_t)cout << 2) + u) * 8 + (c & 7);
    wb2[dst] = f2bf(val);
}

// ---------------- conv1 (512->128, 3x3) via bf16 MFMA implicit GEMM ----------------
__global__ __launch_bounds__(256) void conv1_mfma(
    const unsigned short* __restrict__ xT,
    const unsigned short* __restrict__ wb2p, const unsigned short* __restrict__ wb2c,
    const float* __restrict__ b1p, const float* __restrict__ b1c,
    float* __restrict__ yp, float* __restrict__ yc,
    const unsigned short* __restrict__ zbuf)
{
    const int b = blockIdx.x >> 5;
    const int h0 = (blockIdx.x & 31) * 2;
    const bool isC = (blockIdx.y >> 1) != 0;
    const int ohalf = blockIdx.y & 1;
    const int obase = ohalf << 6;
    const unsigned short* __restrict__ wb2 = isC ? wb2c : wb2p;
    const float* __restrict__ bias = isC ? b1c : b1p;
    float* __restrict__ y = isC ? yc : yp;

    const int t = threadIdx.x;
    const int wid = t >> 6, lane = t & 63;
    const int lhi = lane >> 4, llo = lane & 15;

    __shared__ __align__(16) unsigned short lds_x[8192];
    __shared__ __align__(16) unsigned short lds_w[6144];

    f32x4 acc[4][2];
#pragma unroll
    for (int i = 0; i < 4; ++i)
#pragma unroll
        for (int j = 0; j < 2; ++j) acc[i][j] = (f32x4)0.0f;

    for (int cc = 0; cc < 16; ++cc) {
        const int cb = cc * 32;
        __syncthreads();
        for (int i = wid; i < 16; i += 4) {
            const int u = (i << 6) + lane;
            const int row = u >> 8;
            const int col = (u >> 2) & 63;
            const int g2 = (u & 3) ^ ((col >> 1) & 3);
            const int xrow = h0 - 1 + row;
            const unsigned short* src = ((unsigned)xrow < 64u)
                ? xT + (((size_t)((b << 6) + xrow) << 6) + col) * 512 + cb + (g2 << 3)
                : zbuf;
            gload_lds16(src, &lds_x[(size_t)i << 9]);
        }
        {
            const unsigned short* ws = wb2 + ((size_t)(cc * 3) * 512 + (ohalf << 8)) * 8;
            for (int i = wid; i < 12; i += 4) {
                const int kw = i >> 2, seg = i & 3;
                gload_lds16(ws + ((size_t)(kw * 512 + (seg << 6) + lane) << 3),
                            &lds_w[(size_t)i << 9]);
            }
        }
        for (int kh = 0; kh < 3; ++kh) {
            if (kh) {
                __syncthreads();
                const unsigned short* ws = wb2 + ((size_t)((kh * 16 + cc) * 3) * 512 + (ohalf << 8)) * 8;
                for (int i = wid; i < 12; i += 4) {
                    const int kw = i >> 2, seg = i & 3;
                    gload_lds16(ws + ((size_t)(kw * 512 + (seg << 6) + lane) << 3),
                                &lds_w[(size_t)i << 9]);
                }
            }
            __syncthreads();
#pragma unroll
            for (int kw = 0; kw < 3; ++kw) {
                bf16x8 afr[4];
#pragma unroll
                for (int mf = 0; mf < 4; ++mf) {
                    const int ocl = (mf << 4) + llo;
                    const int un = (kw << 8) + (ocl << 2) + (lhi ^ ((ocl >> 1) & 3));
                    afr[mf] = *(const bf16x8*)&lds_w[un << 3];
                }
                bf16x8 bfr[2];
#pragma unroll
                for (int nf = 0; nf < 2; ++nf) {
                    const int px = (wid << 5) + (nf << 4) + llo;
                    const int orow = px >> 6;
                    const int wc = (px & 63) + kw - 1;
                    const bool inb = (unsigned)wc < 64u;
                    const int wcc = inb ? wc : 0;
                    const int un = (((orow + kh) << 6) + wcc) * 4 + (lhi ^ ((wcc >> 1) & 3));
                    short8v raw = *(const short8v*)&lds_x[un << 3];
                    short8v zz = {};
                    if (!inb) raw = zz;
                    bfr[nf] = __builtin_bit_cast(bf16x8, raw);
                }
#pragma unroll
                for (int mf = 0; mf < 4; ++mf)
#pragma unroll
                    for (int nf = 0; nf < 2; ++nf)
                        acc[mf][nf] = __builtin_amdgcn_mfma_f32_16x16x32_bf16(
                            afr[mf], bfr[nf], acc[mf][nf], 0, 0, 0);
            }
        }
    }

#pragma unroll
    for (int mf = 0; mf < 4; ++mf) {
#pragma unroll
        for (int r = 0; r < 4; ++r) {
            const int oc = obase + (mf << 4) + (lhi << 2) + r;
            const float bv = bias[oc];
#pragma unroll
            for (int nf = 0; nf < 2; ++nf) {
                const int px = (wid << 5) + (nf << 4) + llo;
                const int hout = h0 + (px >> 6);
                const int colw = px & 63;
                float* dst = y + (((size_t)(b * 128 + oc) << 6) + hout) * 64;
                dst[colw] = fmaxf(acc[mf][nf][r] + bv, 0.f);
            }
        }
    }
}

// ---------------- conv2 pair (128->32 x2, 3x3) fused MFMA ----------------
__global__ __launch_bounds__(256) void conv2_mfma(
    const unsigned short* __restrict__ Pb, const unsigned short* __restrict__ Cb,
    const unsigned short* __restrict__ wbp, const unsigned short* __restrict__ wbc,
    const float* __restrict__ b2p, const float* __restrict__ b2c,
    float* __restrict__ out, const unsigned short* __restrict__ zbuf)
{
    const int b = blockIdx.x >> 5;
    const int h0 = (blockIdx.x & 31) * 2;
    const int t = threadIdx.x;
    const int wid = t >> 6, lane = t & 63;
    const int lhi = lane >> 4, llo = lane & 15;

    __shared__ __align__(16) unsigned short xP[8192];
    __shared__ __align__(16) unsigned short xC[8192];
    __shared__ __align__(16) unsigned short wbuf[2][3072];

    f32x4 accP[2][2], accC[2][2];
#pragma unroll
    for (int i = 0; i < 2; ++i)
#pragma unroll
        for (int j = 0; j < 2; ++j) { accP[i][j] = (f32x4)0.0f; accC[i][j] = (f32x4)0.0f; }

    for (int cc = 0; cc < 4; ++cc) {
        const int cb = cc * 32;
        __syncthreads();
        for (int i = wid; i < 16; i += 4) {
            const int u = (i << 6) + lane;
            const int row = u >> 8;
            const int col = (u >> 2) & 63;
            const int g2 = (u & 3) ^ ((col >> 1) & 3);
            const int xrow = h0 - 1 + row;
            const bool inb = (unsigned)xrow < 64u;
            const size_t off = ((((size_t)((b << 6) + (inb ? xrow : 0)) << 6) + col) << 7) + cb + (g2 << 3);
            gload_lds16(inb ? (Pb + off) : zbuf, &xP[(size_t)i << 9]);
            gload_lds16(inb ? (Cb + off) : zbuf, &xC[(size_t)i << 9]);
        }
        {
            const size_t wb0 = (size_t)(cc * 3) * 1024;
            for (int i = wid; i < 12; i += 4) {
                const int cv = (i >= 6);
                const int ii = i - cv * 6;
                const unsigned short* ws = (cv ? wbc : wbp) + wb0;
                gload_lds16(ws + ((ii << 9) + (lane << 3)), &wbuf[cv][(size_t)ii << 9]);
            }
        }
        for (int kh = 0; kh < 3; ++kh) {
            if (kh) {
                __syncthreads();
                const size_t wb0 = (size_t)((kh * 4 + cc) * 3) * 1024;
                for (int i = wid; i < 12; i += 4) {
                    const int cv = (i >= 6);
                    const int ii = i - cv * 6;
                    const unsigned short* ws = (cv ? wbc : wbp) + wb0;
                    gload_lds16(ws + ((ii << 9) + (lane << 3)), &wbuf[cv][(size_t)ii << 9]);
                }
            }
            __syncthreads();
#pragma unroll
            for (int kw = 0; kw < 3; ++kw) {
                bf16x8 afrP[2], afrC[2];
#pragma unroll
                for (int mf = 0; mf < 2; ++mf) {
                    const int ocl = (mf << 4) + llo;
                    const int un = (kw << 7) + (ocl << 2) + (lhi ^ ((ocl >> 1) & 3));
                    afrP[mf] = *(const bf16x8*)&wbuf[0][un << 3];
                    afrC[mf] = *(const bf16x8*)&wbuf[1][un << 3];
                }
                bf16x8 bfrP[2], bfrC[2];
#pragma unroll
                for (int nf = 0; nf < 2; ++nf) {
                    const int px = (wid << 5) + (nf << 4) + llo;
                    const int orow = px >> 6;
                    const int wc = (px & 63) + kw - 1;
                    const bool inb = (unsigned)wc < 64u;
                    const int wcc = inb ? wc : 0;
                    const int un = (((orow + kh) << 6) + wcc) * 4 + (lhi ^ ((wcc >> 1) & 3));
                    short8v rawP = *(const short8v*)&xP[un << 3];
                    short8v rawC = *(const short8v*)&xC[un << 3];
                    short8v zz = {};
                    if (!inb) { rawP = zz; rawC = zz; }
                    bfrP[nf] = __builtin_bit_cast(bf16x8, rawP);
                    bfrC[nf] = __builtin_bit_cast(bf16x8, rawC);
                }
#pragma unroll
                for (int mf = 0; mf < 2; ++mf)
#pragma unroll
                    for (int nf = 0; nf < 2; ++nf) {
                        accP[mf][nf] = __builtin_amdgcn_mfma_f32_16x16x32_bf16(
                            afrP[mf], bfrP[nf], accP[mf][nf], 0, 0, 0);
                        accC[mf][nf] = __builtin_amdgcn_mfma_f32_16x16x32_bf16(
                            afrC[mf], bfrC[nf], accC[mf][nf], 0, 0, 0);
                    }
            }
        }
    }

#pragma unroll
    for (int mf = 0; mf < 2; ++mf) {
#pragma unroll
        for (int r = 0; r < 4; ++r) {
            const int oc = (mf << 4) + (lhi << 2) + r;
            const float bp = b2p[oc], bc = b2c[oc];
#pragma unroll
            for (int nf = 0; nf < 2; ++nf) {
                const int px = (wid << 5) + (nf << 4) + llo;
                const int hout = h0 + (px >> 6);
                const int colw = px & 63;
                const float val = fmaxf(accP[mf][nf][r] + bp, 0.f)
                                + fmaxf(accC[mf][nf][r] + bc, 0.f);
                out[(((size_t)(b * 32 + oc)) << 12) + (hout << 6) + colw] = val;
            }
        }
    }
}

// ---------------- PAM projections: q(scaled by log2e),k -> bf16 [n][32]; d -> VF ----
__global__ __launch_bounds__(256) void pam_proj(
    const float* __restrict__ yp,
    const float* __restrict__ wb, const float* __restrict__ bbq,
    const float* __restrict__ wc, const float* __restrict__ bck,
    const float* __restrict__ wd, const float* __restrict__ bdv,
    unsigned short* __restrict__ Qb, unsigned short* __restrict__ Kb,
    unsigned short* __restrict__ VFo)
{
    const int b = blockIdx.y;
    const int n0 = blockIdx.x * 64;
    const int t = threadIdx.x;
    const int px = t & 63;
    const int og = t >> 6;

    __shared__ __align__(16) float lds_y[64][64];
    __shared__ __align__(16) float lds_w[64][164];

    float acc[10][4];
#pragma unroll
    for (int s = 0; s < 10; ++s) { acc[s][0] = acc[s][1] = acc[s][2] = acc[s][3] = 0.f; }

    for (int cb = 0; cb < 128; cb += 64) {
        for (int i = t; i < 4096; i += 256) {
            int c = i >> 6, p = i & 63;
            lds_y[c][p] = yp[(((size_t)b * 128 + cb + c) << 12) + n0 + p];
        }
        for (int i = t; i < 160 * 64; i += 256) {
            int c = i & 63, o = i >> 6;
            const float* src = (o < 16) ? (wb + o * 128)
                             : (o < 32) ? (wc + (o - 16) * 128)
                                        : (wd + (o - 32) * 128);
            lds_w[c][o] = src[cb + c];
        }
        __syncthreads();
        for (int c = 0; c < 64; ++c) {
            float yv = lds_y[c][px];
#pragma unroll
            for (int s = 0; s < 10; ++s) {
                const float4 w4 = *(const float4*)&lds_w[c][s * 16 + og * 4];
                acc[s][0] += w4.x * yv; acc[s][1] += w4.y * yv;
                acc[s][2] += w4.z * yv; acc[s][3] += w4.w * yv;
            }
        }
        __syncthreads();
    }
    const int n = n0 + px;
    const size_t qkrow = ((size_t)(b << 12) + n) << 5;
#pragma unroll
    for (int s = 0; s < 10; ++s) {
        const float* bsrc = (s == 0) ? (bbq + og * 4)
                          : (s == 1) ? (bck + og * 4)
                                     : (bdv + (s - 2) * 16 + og * 4);
        const float4 bv4 = *(const float4*)bsrc;
        float v0 = acc[s][0] + bv4.x, v1 = acc[s][1] + bv4.y;
        float v2 = acc[s][2] + bv4.z, v3 = acc[s][3] + bv4.w;
        if (s == 0) { v0 *= LOG2E; v1 *= LOG2E; v2 *= LOG2E; v3 *= LOG2E; }
        if (s < 2) {
            unsigned short* dst = (s == 0) ? Qb : Kb;
            uint2 pk2;
            pk2.x = (unsigned)f2bf(v0) | ((unsigned)f2bf(v1) << 16);
            pk2.y = (unsigned)f2bf(v2) | ((unsigned)f2bf(v3) << 16);
            *(uint2*)&dst[qkrow + (og << 2)] = pk2;
            uint2 z2; z2.x = 0u; z2.y = 0u;
            *(uint2*)&dst[qkrow + 16 + (og << 2)] = z2;
        } else {
            const int cf = s - 2;
            const size_t blk = ((size_t)(b * 128 + (n >> 5)) * 8 + cf) << 9;
            const int gl = ((n >> 2) & 3) << 4;
            const int j = (n & 3) | (((n >> 4) & 1) << 2);
            const float vv[4] = {v0, v1, v2, v3};
#pragma unroll
            for (int u = 0; u < 4; ++u)
                VFo[blk + ((size_t)((gl | (og * 4 + u)) << 3)) + j] = f2bf(vv[u]);
        }
    }
}

// ---------------- PAM fused attention: fixed-shift softmax, branch-free loop ----
// grid (128, B), 512 thr = 8 waves: qg = wid&1 (16 queries), kq = wid>>1 (key quarter).
// All partials share the fixed shift M_FIX -> direct additive combine.
__global__ __launch_bounds__(512, 4) void pam_attn_mfma(
    const unsigned short* __restrict__ Qb, const unsigned short* __restrict__ Kb,
    const unsigned short* __restrict__ VF, const float* __restrict__ yp,
    const float* __restrict__ alpha_p, unsigned short* __restrict__ Pb)
{
    const int b = blockIdx.y;
    const int q0 = blockIdx.x * 32;
    const int t = threadIdx.x;
    const int wid = t >> 6, lane = t & 63;
    const int qg = wid & 1, kq = wid >> 1;
    const int g = lane >> 4, qi = lane & 15;
    const int qw0 = q0 + qg * 16;

    __shared__ float combO[2][3][64][33];
    __shared__ float combL[2][4][16];
    unsigned short* smP = (unsigned short*)combO;

    const bf16x8 qf = *(const bf16x8*)&Qb[(((size_t)(b << 12) + qw0 + qi) << 5) + (g << 3)];
    const unsigned short* __restrict__ Kbase = Kb + ((size_t)b << 17);
    const unsigned short* __restrict__ VFb = VF + ((size_t)b << 19);

    bf16x8 ones;
#pragma unroll
    for (int j = 0; j < 8; ++j) ones[j] = (__bf16)1.0f;

    f32x4 accO[8];
#pragma unroll
    for (int cf = 0; cf < 8; ++cf) accO[cf] = (f32x4)0.0f;
    f32x4 accL = (f32x4)0.0f;

    const int ktbase = kq << 5;               // 32 key-tiles (of 32 keys) per quarter
    #define KF(kt, half) (*(const bf16x8*)&Kbase[((size_t)((((kt) << 5) + (half)) + qi) << 5) + (g << 3)])
    bf16x8 kE0 = KF(ktbase, 0), kO0 = KF(ktbase, 16);
    bf16x8 kE1 = KF(ktbase + 1, 0), kO1 = KF(ktbase + 1, 16);

    for (int g2 = 0; g2 < 16; ++g2) {
        const int kt0 = ktbase + (g2 << 1);
        const unsigned short* vt0 = VFb + ((size_t)kt0 << 12) + (lane << 3);
        const unsigned short* vt1 = vt0 + 4096;
        // VF kt0 loads early (independent of scores)
        bf16x8 va0 = *(const bf16x8*)&vt0[0],    va1 = *(const bf16x8*)&vt0[512];
        bf16x8 va2 = *(const bf16x8*)&vt0[1024], va3 = *(const bf16x8*)&vt0[1536];
        bf16x8 va4 = *(const bf16x8*)&vt0[2048], va5 = *(const bf16x8*)&vt0[2560];
        bf16x8 va6 = *(const bf16x8*)&vt0[3072], va7 = *(const bf16x8*)&vt0[3584];
        f32x4 z = {};
        f32x4 sE0 = __builtin_amdgcn_mfma_f32_16x16x32_bf16(kE0, qf, z, 0, 0, 0);
        f32x4 sO0 = __builtin_amdgcn_mfma_f32_16x16x32_bf16(kO0, qf, z, 0, 0, 0);
        f32x4 sE1 = __builtin_amdgcn_mfma_f32_16x16x32_bf16(kE1, qf, z, 0, 0, 0);
        f32x4 sO1 = __builtin_amdgcn_mfma_f32_16x16x32_bf16(kO1, qf, z, 0, 0, 0);
        // prefetch next pair of K tiles
        const int ktn = (g2 < 15) ? kt0 + 2 : kt0;
        bf16x8 nkE0 = KF(ktn, 0), nkO0 = KF(ktn, 16);
        bf16x8 nkE1 = KF(ktn + 1, 0), nkO1 = KF(ktn + 1, 16);
        // P = 2^(s - M_FIX) -- no max tracking, no branch, no cross-lane ops
        bf16x8 pb0, pb1;
#pragma unroll
        for (int r = 0; r < 4; ++r) {
            pb0[r]     = (__bf16)exp2f(sE0[r] - M_FIX);
            pb0[4 + r] = (__bf16)exp2f(sO0[r] - M_FIX);
            pb1[r]     = (__bf16)exp2f(sE1[r] - M_FIX);
            pb1[4 + r] = (__bf16)exp2f(sO1[r] - M_FIX);
        }
        // PV kt0
        accO[0] = __builtin_amdgcn_mfma_f32_16x16x32_bf16(va0, pb0, accO[0], 0, 0, 0);
        accO[1] = __builtin_amdgcn_mfma_f32_16x16x32_bf16(va1, pb0, accO[1], 0, 0, 0);
        accO[2] = __builtin_amdgcn_mfma_f32_16x16x32_bf16(va2, pb0, accO[2], 0, 0, 0);
        accO[3] = __builtin_amdgcn_mfma_f32_16x16x32_bf16(va3, pb0, accO[3], 0, 0, 0);
        // VF kt1 loads overlap kt0 tail
        bf16x8 vb0 = *(const bf16x8*)&vt1[0],    vb1 = *(const bf16x8*)&vt1[512];
        bf16x8 vb2 = *(const bf16x8*)&vt1[1024], vb3 = *(const bf16x8*)&vt1[1536];
        bf16x8 vb4 = *(const bf16x8*)&vt1[2048], vb5 = *(const bf16x8*)&vt1[2560];
        bf16x8 vb6 = *(const bf16x8*)&vt1[3072], vb7 = *(const bf16x8*)&vt1[3584];
        accO[4] = __builtin_amdgcn_mfma_f32_16x16x32_bf16(va4, pb0, accO[4], 0, 0, 0);
        accO[5] = __builtin_amdgcn_mfma_f32_16x16x32_bf16(va5, pb0, accO[5], 0, 0, 0);
        accO[6] = __builtin_amdgcn_mfma_f32_16x16x32_bf16(va6, pb0, accO[6], 0, 0, 0);
        accO[7] = __builtin_amdgcn_mfma_f32_16x16x32_bf16(va7, pb0, accO[7], 0, 0, 0);
        accL    = __builtin_amdgcn_mfma_f32_16x16x32_bf16(ones, pb0, accL, 0, 0, 0);
        // PV kt1
        accO[0] = __builtin_amdgcn_mfma_f32_16x16x32_bf16(vb0, pb1, accO[0], 0, 0, 0);
        accO[1] = __builtin_amdgcn_mfma_f32_16x16x32_bf16(vb1, pb1, accO[1], 0, 0, 0);
        accO[2] = __builtin_amdgcn_mfma_f32_16x16x32_bf16(vb2, pb1, accO[2], 0, 0, 0);
        accO[3] = __builtin_amdgcn_mfma_f32_16x16x32_bf16(vb3, pb1, accO[3], 0, 0, 0);
        accO[4] = __builtin_amdgcn_mfma_f32_16x16x32_bf16(vb4, pb1, accO[4], 0, 0, 0);
        accO[5] = __builtin_amdgcn_mfma_f32_16x16x32_bf16(vb5, pb1, accO[5], 0, 0, 0);
        accO[6] = __builtin_amdgcn_mfma_f32_16x16x32_bf16(vb6, pb1, accO[6], 0, 0, 0);
        accO[7] = __builtin_amdgcn_mfma_f32_16x16x32_bf16(vb7, pb1, accO[7], 0, 0, 0);
        accL    = __builtin_amdgcn_mfma_f32_16x16x32_bf16(ones, pb1, accL, 0, 0, 0);
        kE0 = nkE0; kO0 = nkO0; kE1 = nkE1; kO1 = nkO1;
    }
    #undef KF

    // ---- combine (all partials share M_FIX: plain adds) ----
    if (lane < 16) combL[qg][kq][lane] = accL[0];
    if (kq > 0) {
#pragma unroll
        for (int cf = 0; cf < 8; ++cf)
#pragma unroll
            for (int r = 0; r < 4; ++r)
                combO[qg][kq - 1][lane][cf * 4 + r] = accO[cf][r];
    }
    __syncthreads();
    float sc = 0.f;
    if (kq == 0) {
#pragma unroll
        for (int k2 = 0; k2 < 3; ++k2)
#pragma unroll
            for (int cf = 0; cf < 8; ++cf)
#pragma unroll
                for (int r = 0; r < 4; ++r)
                    accO[cf][r] += combO[qg][k2][lane][cf * 4 + r];
        const float l = combL[qg][0][qi] + combL[qg][1][qi]
                      + combL[qg][2][qi] + combL[qg][3][qi];
        sc = alpha_p[0] / l;
    }
    __syncthreads();              // all combO reads done; safe to reuse as smP
    if (kq == 0) {
#pragma unroll
        for (int cf = 0; cf < 8; ++cf) {
#pragma unroll
            for (int r = 0; r < 4; ++r) {
                const int ch = cf * 16 + (g << 2) + r;
                const size_t o = (((size_t)(b * 128 + ch)) << 12) + qw0 + qi;
                const float val = accO[cf][r] * sc + yp[o];
                smP[(qg * 16 + qi) * 128 + ch] = f2bf(val);
            }
        }
    }
    __syncthreads();
    unsigned* Pb32 = (unsigned*)Pb;
    const unsigned* sm32 = (const unsigned*)smP;
    for (int i = t; i < 2048; i += 512) {
        const int row = i >> 6, u = i & 63;
        Pb32[((size_t)(b << 12) + q0 + row) * 64 + u] = sm32[i];
    }
}

// ---------------- CAM Gram via MFMA, bf16 hi/lo split (fp32-accurate) ----------
__global__ __launch_bounds__(256) void cam_gram_mfma(const float* __restrict__ yc,
                                                     float* __restrict__ GP)
{
    const int kb = blockIdx.x, b = blockIdx.y;
    const int t = threadIdx.x;
    const int wid = t >> 6, lane = t & 63;
    const int lhi = lane >> 4, llo = lane & 15;
    const int mr = (wid & 1) << 6, nr = (wid >> 1) << 6;
    const float* __restrict__ Y = yc + ((size_t)b << 19);

    f32x4 acc[4][4];
#pragma unroll
    for (int i = 0; i < 4; ++i)
#pragma unroll
        for (int j = 0; j < 4; ++j) acc[i][j] = (f32x4)0.0f;

    for (int ks = 0; ks < 8; ++ks) {
        const int n0 = (kb << 8) + (ks << 5) + (lhi << 3);
        bf16x8 ah[4], al[4], bh[4], bl[4];
#pragma unroll
        for (int mf = 0; mf < 4; ++mf) {
            const int row = mr + (mf << 4) + llo;
            const float* p = &Y[((size_t)row << 12) + n0];
            const float4 v0 = *(const float4*)p;
            const float4 v1 = *(const float4*)(p + 4);
            const float vv[8] = {v0.x, v0.y, v0.z, v0.w, v1.x, v1.y, v1.z, v1.w};
#pragma unroll
            for (int j = 0; j < 8; ++j) {
                const __bf16 h = (__bf16)vv[j];
                ah[mf][j] = h;
                al[mf][j] = (__bf16)(vv[j] - (float)h);
            }
        }
#pragma unroll
        for (int nf = 0; nf < 4; ++nf) {
            const int row = nr + (nf << 4) + llo;
            const float* p = &Y[((size_t)row << 12) + n0];
            const float4 v0 = *(const float4*)p;
            const float4 v1 = *(const float4*)(p + 4);
            const float vv[8] = {v0.x, v0.y, v0.z, v0.w, v1.x, v1.y, v1.z, v1.w};
#pragma unroll
            for (int j = 0; j < 8; ++j) {
                const __bf16 h = (__bf16)vv[j];
                bh[nf][j] = h;
                bl[nf][j] = (__bf16)(vv[j] - (float)h);
            }
        }
#pragma unroll
        for (int mf = 0; mf < 4; ++mf)
#pragma unroll
            for (int nf = 0; nf < 4; ++nf) {
                acc[mf][nf] = __builtin_amdgcn_mfma_f32_16x16x32_bf16(ah[mf], bh[nf], acc[mf][nf], 0, 0, 0);
                acc[mf][nf] = __builtin_amdgcn_mfma_f32_16x16x32_bf16(ah[mf], bl[nf], acc[mf][nf], 0, 0, 0);
                acc[mf][nf] = __builtin_amdgcn_mfma_f32_16x16x32_bf16(al[mf], bh[nf], acc[mf][nf], 0, 0, 0);
            }
    }
    const size_t base = ((size_t)((b << 4) + kb) << 14);
#pragma unroll
    for (int mf = 0; mf < 4; ++mf)
#pragma unroll
        for (int nf = 0; nf < 4; ++nf)
#pragma unroll
            for (int r = 0; r < 4; ++r) {
                const int c = mr + (mf << 4) + (lhi << 2) + r;
                const int d = nr + (nf << 4) + llo;
                GP[base + ((size_t)c << 7) + d] = acc[mf][nf][r];
            }
}

__global__ __launch_bounds__(256) void cam_gram_reduce(const float* __restrict__ GP,
                                                       float* __restrict__ G)
{
    const int b = blockIdx.y;
    const int i0 = blockIdx.x * 1024 + threadIdx.x * 4;
    float4 s = make_float4(0.f, 0.f, 0.f, 0.f);
#pragma unroll
    for (int kb = 0; kb < 16; ++kb) {
        const float4 v = *(const float4*)&GP[((size_t)((b << 4) + kb) << 14) + i0];
        s.x += v.x; s.y += v.y; s.z += v.z; s.w += v.w;
    }
    *(float4*)&G[((size_t)b << 14) + i0] = s;
}

// ---------------- CAM: softmax + apply + beta residual -> Cb bf16 [b][n][128] ----
__global__ __launch_bounds__(256) void cam_apply(
    const float* __restrict__ G, const float* __restrict__ yc,
    const float* __restrict__ beta_p, unsigned short* __restrict__ Cb)
{
    const int b = blockIdx.y;
    const int cchunk = blockIdx.x >> 4;
    const int ns = blockIdx.x & 15;
    const int t = threadIdx.x;

    __shared__ float att_t[128][32];
    __shared__ float s_buf[128 * 64];
    __shared__ unsigned short smC[64 * 32];

    for (int i = t; i < 4096; i += 256)
        s_buf[i] = G[((size_t)b << 14) + (size_t)cchunk * 32 * 128 + i];
    __syncthreads();
    {
        const int r = t >> 3, seg = t & 7;
        float vals[16];
        float gmin = 3.0e38f;
#pragma unroll
        for (int u = 0; u < 16; ++u) {
            vals[u] = s_buf[r * 128 + seg * 16 + u];
            gmin = fminf(gmin, vals[u]);
        }
        gmin = fminf(gmin, __shfl_xor(gmin, 1));
        gmin = fminf(gmin, __shfl_xor(gmin, 2));
        gmin = fminf(gmin, __shfl_xor(gmin, 4));
        float sum = 0.f;
#pragma unroll
        for (int u = 0; u < 16; ++u) { vals[u] = __expf(gmin - vals[u]); sum += vals[u]; }
        sum += __shfl_xor(sum, 1);
        sum += __shfl_xor(sum, 2);
        sum += __shfl_xor(sum, 4);
        const float inv = 1.f / sum;
#pragma unroll
        for (int u = 0; u < 16; ++u)
            att_t[seg * 16 + u][r] = vals[u] * inv;
    }
    __syncthreads();

    const float be = beta_p[0];
    const int nc = t & 31, cgp = t >> 5;
    unsigned* Cb32 = (unsigned*)Cb;
    const unsigned* smC32 = (const unsigned*)smC;
    for (int chunk = 0; chunk < 4; ++chunk) {
        const int nb = ns * 256 + chunk * 64;
        for (int i = t; i < 8192; i += 256) {
            int d = i >> 6, nn = i & 63;
            s_buf[d * 64 + nn] = yc[(((size_t)b * 128 + d) << 12) + nb + nn];
        }
        __syncthreads();
        float a0[4] = {0, 0, 0, 0}, a1[4] = {0, 0, 0, 0};
        for (int d = 0; d < 128; ++d) {
            const float y0 = s_buf[d * 64 + nc];
            const float y1 = s_buf[d * 64 + nc + 32];
#pragma unroll
            for (int o = 0; o < 4; ++o) {
                const float wv = att_t[d][cgp * 4 + o];
                a0[o] += wv * y0; a1[o] += wv * y1;
            }
        }
#pragma unroll
        for (int o = 0; o < 4; ++o) {
            const int cl = cgp * 4 + o;
            const int c = cchunk * 32 + cl;
            smC[nc * 32 + cl]        = f2bf(be * a0[o] + s_buf[c * 64 + nc]);
            smC[(nc + 32) * 32 + cl] = f2bf(be * a1[o] + s_buf[c * 64 + nc + 32]);
        }
        __syncthreads();
        for (int i = t; i < 1024; i += 256) {
            const int row = i >> 4, u = i & 15;
            Cb32[((size_t)(b << 12) + nb + row) * 64 + (cchunk << 4) + u] = smC32[i];
        }
        __syncthreads();
    }
}

// ---------------- launcher ----------------
extern "C" void kernel_launch(void* const* d_in, const int* in_sizes, int n_in,
                              void* d_out, int out_size, void* d_ws, size_t ws_size,
                              hipStream_t stream)
{
    (void)in_sizes; (void)n_in; (void)out_size; (void)ws_size;
    const float* x    = (const float*)d_in[0];
    const float* wp1  = (const float*)d_in[1];
    const float* gp1  = (const float*)d_in[2];
    const float* bp1  = (const float*)d_in[3];
    const float* mp1  = (const float*)d_in[4];
    const float* vp1  = (const float*)d_in[5];
    const float* wc1  = (const float*)d_in[6];
    const float* gc1  = (const float*)d_in[7];
    const float* bc1  = (const float*)d_in[8];
    const float* mc1  = (const float*)d_in[9];
    const float* vc1  = (const float*)d_in[10];
    const float* pwb  = (const float*)d_in[11];
    const float* pbb  = (const float*)d_in[12];
    const float* pwc  = (const float*)d_in[13];
    const float* pbc  = (const float*)d_in[14];
    const float* pwd  = (const float*)d_in[15];
    const float* pbd  = (const float*)d_in[16];
    const float* alpha= (const float*)d_in[17];
    const float* beta = (const float*)d_in[18];
    const float* wp2  = (const float*)d_in[19];
    const float* gp2  = (const float*)d_in[20];
    const float* bp2  = (const float*)d_in[21];
    const float* mp2  = (const float*)d_in[22];
    const float* vp2  = (const float*)d_in[23];
    const float* wc2  = (const float*)d_in[24];
    const float* gc2  = (const float*)d_in[25];
    const float* bc2  = (const float*)d_in[26];
    const float* mc2  = (const float*)d_in[27];
    const float* vc2  = (const float*)d_in[28];

    float* W = (float*)d_ws;
    unsigned short* wb2p16 = (unsigned short*)(W + OFF_WB2P);
    unsigned short* wb2c16 = (unsigned short*)(W + OFF_WB2C);
    float* b1p = W + OFF_B1P;
    float* b1c = W + OFF_B1C;
    unsigned short* wt2p16 = (unsigned short*)(W + OFF_WT2P);
    unsigned short* wt2c16 = (unsigned short*)(W + OFF_WT2C);
    float* b2p = W + OFF_B2P;
    float* b2c = W + OFF_B2C;
    float* yp   = W + OFF_YP;
    float* yc   = W + OFF_YC;
    unsigned short* Qb16 = (unsigned short*)(W + OFF_Q);
    unsigned short* Kb16 = (unsigned short*)(W + OFF_K);
    unsigned short* VF16 = (unsigned short*)(W + OFF_V);
    unsigned short* Pb16 = (unsigned short*)(W + OFF_PB);
    unsigned short* Cb16 = (unsigned short*)(W + OFF_CB);
    float* GP   = W + OFF_GP;
    float* G    = W + OFF_G;
    unsigned short* xT16  = (unsigned short*)(W + OFF_PB);  // alias, dead after conv1
    unsigned short* zb16  = (unsigned short*)(W + OFF_Z);
    float* out  = (float*)d_out;

    hipMemsetAsync(zb16, 0, 4096 * sizeof(float), stream);

    x_transpose<<<dim3(64, 4, 4), 256, 0, stream>>>(x, xT16);
    prep_conv_mfma<<<dim3(2304, 2), 256, 0, stream>>>(
        wp1, gp1, bp1, mp1, vp1, wc1, gc1, bc1, mc1, vc1,
        wb2p16, wb2c16, b1p, b1c, 512, 128);
    prep_conv_mfma<<<dim3(144, 2), 256, 0, stream>>>(
        wp2, gp2, bp2, mp2, vp2, wc2, gc2, bc2, mc2, vc2,
        wt2p16, wt2c16, b2p, b2c, 128, 32);

    conv1_mfma<<<dim3(128, 4), 256, 0, stream>>>(xT16, wb2p16, wb2c16, b1p, b1c, yp, yc, zb16);

    pam_proj<<<dim3(64, 4), 256, 0, stream>>>(yp, pwb, pbb, pwc, pbc, pwd, pbd, Qb16, Kb16, VF16);
    pam_attn_mfma<<<dim3(128, 4), 512, 0, stream>>>(Qb16, Kb16, VF16, yp, alpha, Pb16);

    cam_gram_mfma<<<dim3(16, 4), 256, 0, stream>>>(yc, GP);
    cam_gram_reduce<<<dim3(16, 4), 256, 0, stream>>>(GP, G);
    cam_apply<<<dim3(64, 4), 256, 0, stream>>>(G, yc, beta, Cb16);

    conv2_mfma<<<128, 256, 0, stream>>>(Pb16, Cb16, wt2p16, wt2c16, b2p, b2c, out, zb16);
}